// Round 8
// baseline (266.588 us; speedup 1.0000x reference)
//
#include <hip/hip_runtime.h>
#include <hip/hip_bf16.h>
#include <stdint.h>
#include <stddef.h>

#define HH_EPS 1e-8f

typedef __attribute__((ext_vector_type(8))) short short8;
typedef __attribute__((ext_vector_type(4))) float f32x4;
typedef __attribute__((ext_vector_type(2))) unsigned int uint2_t;

#define CDIM 512
#define SDIM 4096
#define BN 128
#define BK 32
#define NSTEP 16      // CDIM / BK

// ---------------------------------------------------------------------------
// Frag-tiled W (blocking-agnostic): fragment id = (c>>5)*32 + (o>>4);
// within a fragment: lane = ((c>>3)&3)*16 + (o&15), elem = c&7.
// Fragment = 64 lanes x 16 B = 1 KB contiguous in exact B-operand lane order.
// ---------------------------------------------------------------------------
__device__ __forceinline__ size_t wt_idx(int o, int c) {
    return (((size_t)(c >> 5) * 32 + (o >> 4)) * 64
            + (size_t)((c >> 3) & 3) * 16 + (o & 15)) * 8 + (c & 7);
}

// ---------------------------------------------------------------------------
// Kernel 1: W = H_32 ... H_1, column-parallel, on-the-fly normalization.
// ---------------------------------------------------------------------------
__global__ void compute_w(const float* __restrict__ V,
                          __hip_bfloat16* __restrict__ Wt) {
    const int wave = threadIdx.x >> 6;
    const int lane = threadIdx.x & 63;
    const int jA = (blockIdx.x * 4 + wave) * 2;
    const int jB = jA + 1;
    const int ib = lane * 8;

    float wA[8], wB[8];
    #pragma unroll
    for (int r = 0; r < 8; r++) {
        wA[r] = (ib + r == jA) ? 1.0f : 0.0f;
        wB[r] = (ib + r == jB) ? 1.0f : 0.0f;
    }
    float4 c0 = *(const float4*)(V + ib);
    float4 c1 = *(const float4*)(V + ib + 4);

    for (int k = 0; k < 32; k++) {
        const float v[8] = {c0.x, c0.y, c0.z, c0.w, c1.x, c1.y, c1.z, c1.w};
        if (k < 31) {
            c0 = *(const float4*)(V + (size_t)(k + 1) * 512 + ib);
            c1 = *(const float4*)(V + (size_t)(k + 1) * 512 + ib + 4);
        }
        float dA = 0.0f, dB = 0.0f, ss = 0.0f;
        #pragma unroll
        for (int r = 0; r < 8; r++) {
            dA += v[r] * wA[r];
            dB += v[r] * wB[r];
            ss += v[r] * v[r];
        }
        #pragma unroll
        for (int off = 32; off > 0; off >>= 1) {
            dA += __shfl_xor(dA, off);
            dB += __shfl_xor(dB, off);
            ss += __shfl_xor(ss, off);
        }
        const float t = sqrtf(ss) + HH_EPS;
        const float scale = 2.0f / (t * t);
        const float tA = scale * dA, tB = scale * dB;
        #pragma unroll
        for (int r = 0; r < 8; r++) {
            wA[r] -= tA * v[r];
            wB[r] -= tB * v[r];
        }
    }
    #pragma unroll
    for (int r = 0; r < 8; r++) {
        Wt[wt_idx(ib + r, jA)] = __float2bfloat16(wA[r]);
        Wt[wt_idx(ib + r, jB)] = __float2bfloat16(wB[r]);
    }
}

__device__ __forceinline__ void lds_barrier() {
    // lgkmcnt(0) only: my LDS ops retired; global loads stay in flight.
    __builtin_amdgcn_s_waitcnt(0xC07F);
    __builtin_amdgcn_s_barrier();
}

__device__ __forceinline__ unsigned int bf16u(float f) {
    __hip_bfloat16 h = __float2bfloat16(f);
    return (unsigned int)*(unsigned short*)&h;
}

// ---------------------------------------------------------------------------
// Kernel 2: out[b] = W @ x[b].  IN-FLIGHT-BYTES design.
// Evidence v0-v7: plateau 81-99 us tracks (bytes in flight/CU)/latency;
// all prior variants gathered x as 4 B/lane strided dwords.  v8 loads x
// ROW-MAJOR dwordx4 (16 B/lane, 1 KB/wave-instr, dist-3 ring -> ~3 KB/wave
// in flight), k-packs via 4x shfl_xor in-register 4x4 bf16 transpose, and
// writes ONE b64 to the same verified frag-ordered LDS layout.
// Tile o512 x n128, 1024 thr / 16 waves, wave = 32o x 128n, acc 64 AGPR.
// W: direct L2->VGPR dwordx4 frags, dbuf dist-1 (v6 verbatim).
// XCD-chunked block swizzle: 512 blocks, 64/XCD = 2 full batches/XCD.
// ---------------------------------------------------------------------------
__global__ __launch_bounds__(1024, 4) void hh_gemm(
    const float* __restrict__ x,
    const __hip_bfloat16* __restrict__ Wt,
    float* __restrict__ out)
{
    __shared__ __attribute__((aligned(16))) __hip_bfloat16 Bbuf[2][BN * BK]; // 2 x 8 KB

    const int tid  = threadIdx.x;
    const int wave = tid >> 6, lane = tid & 63;
    const int quad = lane >> 4, l16 = lane & 15;

    // XCD-chunked swizzle (bijective: 512 % 8 == 0)
    const int bid = (blockIdx.x & 7) * 64 + (blockIdx.x >> 3);
    const int b   = bid >> 5;            // 0..15
    const int nt  = bid & 31;            // 0..31
    const int n0  = nt * BN;

    // ---- x staging mapping (row-major loads + shfl transpose) ----
    // thread (w=wave, l=lane): k_local = (w&7)*4 + (l>>4), n_loc = (w>>3)*64
    // + (l&15)*4.  Load float4 = x[k][n_loc..+3] (16 consecutive lanes ->
    // 256 B contiguous).  After xor16/xor32 transpose, lane holds the
    // k-quad column for n = n_loc + (l>>4)  -> single 8 B LDS write.
    const int r_t    = lane >> 4;                    // 0..3 (transpose row)
    const int kbase  = (wave & 7) * 4;               // k-quad base
    const int k_loc  = kbase + r_t;
    const int n_loc  = (wave >> 3) * 64 + l16 * 4;
    const float* xp0 = x + (size_t)b * CDIM * SDIM
                         + (size_t)k_loc * SDIM + n0 + n_loc;
    // post-transpose n and LDS slot (short units)
    const int n_tr   = (wave >> 3) * 64 + l16 * 4 + r_t;
    const size_t wslot = ((size_t)(n_tr >> 4) * 64
                          + (size_t)((wave & 7) >> 1) * 16 + (n_tr & 15)) * 8
                         + (size_t)(wave & 1) * 4;

    // W frags: wave owns o-rows wave*32..+31 -> frag ids kt*32 + wave*2 + oi
    const short8* wp = (const short8*)Wt + (size_t)(wave * 2) * 64 + lane;

    f32x4 acc[8][2];                     // [mi = n-frag][oi = o-frag]
    #pragma unroll
    for (int mi = 0; mi < 8; mi++)
        #pragma unroll
        for (int oi = 0; oi < 2; oi++) {
            f32x4 z = {0.0f, 0.0f, 0.0f, 0.0f};
            acc[mi][oi] = z;
        }

    float4 pfX[3];                       // dist-3 x ring (12 VGPR)
    short8 wb[2][2];                     // dist-1 W dbuf (16 VGPR)

    auto loadX = [&](int kt, int s) {
        pfX[s] = *(const float4*)(xp0 + (size_t)kt * BK * SDIM);
    };
    auto loadW = [&](int kt, int s) {
        const short8* p = wp + (size_t)kt * 32 * 64;
        wb[s][0] = p[0];
        wb[s][1] = p[64];
    };
    auto writeB = [&](int buf, int s) {
        const float4 v = pfX[s];
        unsigned int A = bf16u(v.x) | (bf16u(v.y) << 16);   // (M[r][0],M[r][1])
        unsigned int B = bf16u(v.z) | (bf16u(v.w) << 16);   // (M[r][2],M[r][3])
        // stage 1: partner r^1 (lane xor 16)
        const unsigned int A1 = __shfl_xor((int)A, 16);
        const unsigned int B1 = __shfl_xor((int)B, 16);
        unsigned int pA, pB;
        if ((r_t & 1) == 0) {
            pA = (A & 0xffffu) | (A1 << 16);                // col0 rows r,r+1
            pB = (B & 0xffffu) | (B1 << 16);                // col2 rows r,r+1
        } else {
            pA = (A1 >> 16) | (A & 0xffff0000u);            // col1 rows r-1,r
            pB = (B1 >> 16) | (B & 0xffff0000u);            // col3 rows r-1,r
        }
        // stage 2: partner r^2 (lane xor 32)
        const unsigned int pA2 = __shfl_xor((int)pA, 32);
        const unsigned int pB2 = __shfl_xor((int)pB, 32);
        uint2_t w2;
        if (r_t < 2) { w2[0] = pA;  w2[1] = pA2; }          // column r (0/1)
        else         { w2[0] = pB2; w2[1] = pB;  }          // column r (2/3)
        *(uint2_t*)(&Bbuf[buf][wslot]) = w2;                // one b64 write
    };

    // ---- prologue: X(0..2) + W(0) in flight; X(0) -> LDS0 ----
    loadX(0, 0);
    loadX(1, 1);
    loadX(2, 2);
    loadW(0, 0);
    writeB(0, 0);         // compiler vmcnt retires X(0); X(1,2),W(0) fly
    lds_barrier();

    #pragma unroll
    for (int kt = 0; kt < NSTEP; kt++) {
        const int p = kt & 1, w = kt & 1;
        if (kt + 1 < NSTEP) loadW(kt + 1, w ^ 1);    // hides under this step
        if (kt + 3 < NSTEP) loadX(kt + 3, kt % 3);   // ring slot freed
        #pragma unroll
        for (int mi = 0; mi < 8; mi++) {
            const short8 afr =
                *(const short8*)(&Bbuf[p][(size_t)(mi * 64 + lane) * 8]);
            acc[mi][0] = __builtin_amdgcn_mfma_f32_16x16x32_bf16(
                afr, wb[w][0], acc[mi][0], 0, 0, 0);
            acc[mi][1] = __builtin_amdgcn_mfma_f32_16x16x32_bf16(
                afr, wb[w][1], acc[mi][1], 0, 0, 0);
        }
        if (kt + 1 < NSTEP) {
            writeB(p ^ 1, (kt + 1) % 3);
            lds_barrier();
        }
    }

    // ---- epilogue: D col = o (l16), reg axis = contiguous n -> float4 ----
    float* ob = out + (size_t)b * CDIM * SDIM + n0;
    #pragma unroll
    for (int oi = 0; oi < 2; oi++) {
        const int o = wave * 32 + oi * 16 + l16;
        #pragma unroll
        for (int mi = 0; mi < 8; mi++)
            *(f32x4*)(ob + (size_t)o * SDIM + mi * 16 + quad * 4) = acc[mi][oi];
    }
}

// ---------------------------------------------------------------------------
extern "C" void kernel_launch(void* const* d_in, const int* in_sizes, int n_in,
                              void* d_out, int out_size, void* d_ws, size_t ws_size,
                              hipStream_t stream) {
    const float* x = (const float*)d_in[0];   // [16, 512, 64, 64]
    const float* V = (const float*)d_in[1];   // [32, 512]
    float* out = (float*)d_out;               // [16, 512, 64, 64] fp32

    __hip_bfloat16* Wt = (__hip_bfloat16*)d_ws;   // 512 KB frag-tiled W

    compute_w<<<64, 256, 0, stream>>>(V, Wt);
    hh_gemm<<<512, 1024, 0, stream>>>(x, Wt, out);
}

// Round 9
// 259.365 us; speedup vs baseline: 1.0279x; 1.0279x over previous
//
#include <hip/hip_runtime.h>
#include <hip/hip_bf16.h>
#include <stdint.h>
#include <stddef.h>

#define HH_EPS 1e-8f

typedef __attribute__((ext_vector_type(8))) short short8;
typedef __attribute__((ext_vector_type(4))) short short4_t;
typedef __attribute__((ext_vector_type(4))) float f32x4;

#define CDIM 512
#define SDIM 4096
#define BN 128
#define BK 32
#define NSTEP 16      // CDIM / BK

// ---------------------------------------------------------------------------
// Frag-tiled W (blocking-agnostic): fragment id = (c>>5)*32 + (o>>4);
// within a fragment: lane = ((c>>3)&3)*16 + (o&15), elem = c&7.
// Fragment = 64 lanes x 16 B = 1 KB contiguous in exact B-operand lane order.
// ---------------------------------------------------------------------------
__device__ __forceinline__ size_t wt_idx(int o, int c) {
    return (((size_t)(c >> 5) * 32 + (o >> 4)) * 64
            + (size_t)((c >> 3) & 3) * 16 + (o & 15)) * 8 + (c & 7);
}

// ---------------------------------------------------------------------------
// Kernel 1: W = H_32 ... H_1, column-parallel, on-the-fly normalization.
// ---------------------------------------------------------------------------
__global__ void compute_w(const float* __restrict__ V,
                          __hip_bfloat16* __restrict__ Wt) {
    const int wave = threadIdx.x >> 6;
    const int lane = threadIdx.x & 63;
    const int jA = (blockIdx.x * 4 + wave) * 2;
    const int jB = jA + 1;
    const int ib = lane * 8;

    float wA[8], wB[8];
    #pragma unroll
    for (int r = 0; r < 8; r++) {
        wA[r] = (ib + r == jA) ? 1.0f : 0.0f;
        wB[r] = (ib + r == jB) ? 1.0f : 0.0f;
    }
    float4 c0 = *(const float4*)(V + ib);
    float4 c1 = *(const float4*)(V + ib + 4);

    for (int k = 0; k < 32; k++) {
        const float v[8] = {c0.x, c0.y, c0.z, c0.w, c1.x, c1.y, c1.z, c1.w};
        if (k < 31) {
            c0 = *(const float4*)(V + (size_t)(k + 1) * 512 + ib);
            c1 = *(const float4*)(V + (size_t)(k + 1) * 512 + ib + 4);
        }
        float dA = 0.0f, dB = 0.0f, ss = 0.0f;
        #pragma unroll
        for (int r = 0; r < 8; r++) {
            dA += v[r] * wA[r];
            dB += v[r] * wB[r];
            ss += v[r] * v[r];
        }
        #pragma unroll
        for (int off = 32; off > 0; off >>= 1) {
            dA += __shfl_xor(dA, off);
            dB += __shfl_xor(dB, off);
            ss += __shfl_xor(ss, off);
        }
        const float t = sqrtf(ss) + HH_EPS;
        const float scale = 2.0f / (t * t);
        const float tA = scale * dA, tB = scale * dB;
        #pragma unroll
        for (int r = 0; r < 8; r++) {
            wA[r] -= tA * v[r];
            wB[r] -= tB * v[r];
        }
    }
    #pragma unroll
    for (int r = 0; r < 8; r++) {
        Wt[wt_idx(ib + r, jA)] = __float2bfloat16(wA[r]);
        Wt[wt_idx(ib + r, jB)] = __float2bfloat16(wB[r]);
    }
}

__device__ __forceinline__ void lds_barrier() {
    // lgkmcnt(0) only: my LDS ops retired; global loads stay in flight.
    __builtin_amdgcn_s_waitcnt(0xC07F);
    __builtin_amdgcn_s_barrier();
}

// ---------------------------------------------------------------------------
// Kernel 2: out[b] = W @ x[b].  8-PHASE FINE INTERLEAVE (T3+T5+T14) on the
// v6 geometry (best base, 82 us).  Evidence: v6 block-step = 12,300 cy vs
// 4,300 cy of pipe work -> 65% exposed sync wait; m233: 2-phase loops are
// ~72% stage/sync overhead; v7 proved work-per-barrier is NOT the dial
// (m196: coarse split hurts, fine interleave is the lever).
// Each K-step -> 4 phases: {2 ds_read || one stage-slice; barrier; lgkm(0);
// setprio(1); 4-MFMA cluster; setprio(0); barrier}.  Stage slices:
// ph0 loadW(kt+1) / ph1 loadB-issue(kt+2) / ph2 cvt-pack / ph3 LDS-write
// (issue-early, write-late = T14).  Reads+stage of phase q+1 hide under
// other waves' MFMA of phase q.
// Geometry (v6 verbatim): 1024 thr / 16 waves, wave = 32o x 128n,
// acc[8][2] = 64 AGPR; W direct-L2 dwordx4 dbuf; x gather->cvt->frag LDS.
// ---------------------------------------------------------------------------
__global__ __launch_bounds__(1024, 4) void hh_gemm(
    const float* __restrict__ x,
    const __hip_bfloat16* __restrict__ Wt,
    float* __restrict__ out)
{
    __shared__ __attribute__((aligned(16))) __hip_bfloat16 Bbuf[2][BN * BK]; // 2 x 8 KB

    const int tid  = threadIdx.x;
    const int wave = tid >> 6, lane = tid & 63;
    const int quad = lane >> 4, l16 = lane & 15;

    const int bid = blockIdx.x;          // 0..511
    const int b   = bid >> 5;            // 0..15
    const int nt  = bid & 31;            // 0..31
    const int n0  = nt * BN;

    // x staging: col c = tid&127; rows r = (tid>>7)*4 + j, j=0..3
    const int c_s  = tid & 127;
    const int r0_s = (tid >> 7) * 4;                 // 0,4,8,...,28
    const int kq_s = tid >> 8;                       // r>>3  (0..3)
    const int h_s  = (tid >> 7) & 1;                 // (r>>2)&1
    const float* xp0 = x + (size_t)b * CDIM * SDIM
                         + (size_t)r0_s * SDIM + n0 + c_s;
    const size_t wslot = (size_t)(c_s >> 4) * 512
                       + (size_t)(kq_s * 16 + (c_s & 15)) * 8 + h_s * 4;

    // W frags: wave owns o-rows wave*32..+31 -> frag ids kt*32 + wave*2 + oi
    const short8* wp = (const short8*)Wt + (size_t)(wave * 2) * 64 + lane;

    f32x4 acc[8][2];                     // [mi = n-frag][oi = o-frag]
    #pragma unroll
    for (int mi = 0; mi < 8; mi++)
        #pragma unroll
        for (int oi = 0; oi < 2; oi++) {
            f32x4 z = {0.0f, 0.0f, 0.0f, 0.0f};
            acc[mi][oi] = z;
        }

    float    pfB[2][4];                  // dist-2 x stage ring (8 VGPR)
    short8   wb[2][2];                   // dist-1 W dbuf (16 VGPR)
    short4_t pk;                         // packed 8 B staged for write-late

    auto loadB = [&](int kt, int s) {
        const float* p = xp0 + (size_t)kt * BK * SDIM;
        #pragma unroll
        for (int j = 0; j < 4; j++) pfB[s][j] = p[(size_t)j * SDIM];
    };
    auto packB = [&](int s) {            // cvt only (VALU) — T14 early half
        #pragma unroll
        for (int j = 0; j < 4; j++) {
            __hip_bfloat16 h = __float2bfloat16(pfB[s][j]);
            pk[j] = *(const short*)&h;
        }
    };
    auto writePK = [&](int buf) {        // T14 late half: one 8 B LDS write
        *(short4_t*)(&Bbuf[buf][wslot]) = pk;
    };
    auto loadW = [&](int kt, int s) {
        const short8* p = wp + (size_t)kt * 32 * 64;
        wb[s][0] = p[0];
        wb[s][1] = p[64];
    };

#define MFMA1(A, MI, OI)                                                       \
    acc[MI][OI] = __builtin_amdgcn_mfma_f32_16x16x32_bf16(                     \
        A, wb[P_][OI], acc[MI][OI], 0, 0, 0);

#define PHASE(P_, Q, STAGE)                                                    \
    {                                                                          \
        const short8 a0 = *(const short8*)(                                    \
            &Bbuf[P_][(size_t)(((Q) * 2 + 0) * 64 + lane) * 8]);               \
        const short8 a1 = *(const short8*)(                                    \
            &Bbuf[P_][(size_t)(((Q) * 2 + 1) * 64 + lane) * 8]);               \
        STAGE;                                                                 \
        __builtin_amdgcn_s_barrier();                                          \
        __builtin_amdgcn_s_waitcnt(0xC07F);  /* lgkm(0): a0,a1 (+writes) */    \
        __builtin_amdgcn_s_setprio(1);                                         \
        acc[(Q)*2+0][0] = __builtin_amdgcn_mfma_f32_16x16x32_bf16(             \
            a0, wb[P_][0], acc[(Q)*2+0][0], 0, 0, 0);                          \
        acc[(Q)*2+0][1] = __builtin_amdgcn_mfma_f32_16x16x32_bf16(             \
            a0, wb[P_][1], acc[(Q)*2+0][1], 0, 0, 0);                          \
        acc[(Q)*2+1][0] = __builtin_amdgcn_mfma_f32_16x16x32_bf16(             \
            a1, wb[P_][0], acc[(Q)*2+1][0], 0, 0, 0);                          \
        acc[(Q)*2+1][1] = __builtin_amdgcn_mfma_f32_16x16x32_bf16(             \
            a1, wb[P_][1], acc[(Q)*2+1][1], 0, 0, 0);                          \
        __builtin_amdgcn_s_setprio(0);                                         \
        __builtin_amdgcn_s_barrier();                                          \
    }

    // ---- prologue: B(0),B(1),W(0) in flight; pack+write B(0) -> LDS0 ----
    loadB(0, 0);
    loadB(1, 1);
    loadW(0, 0);
    packB(0);             // compiler vmcnt retires B(0); B(1),W(0) fly
    writePK(0);
    lds_barrier();

#define DO_STEP(KT)                                                            \
    {                                                                          \
        constexpr int p = (KT) & 1;                                            \
        PHASE(p, 0, if constexpr ((KT) + 1 < NSTEP) loadW((KT) + 1, p ^ 1))    \
        PHASE(p, 1, if constexpr ((KT) + 2 < NSTEP) loadB((KT) + 2, (KT) & 1)) \
        PHASE(p, 2, if constexpr ((KT) + 1 < NSTEP) packB(((KT) + 1) & 1))     \
        PHASE(p, 3, if constexpr ((KT) + 1 < NSTEP) writePK(p ^ 1))            \
    }

    DO_STEP(0)  DO_STEP(1)  DO_STEP(2)  DO_STEP(3)
    DO_STEP(4)  DO_STEP(5)  DO_STEP(6)  DO_STEP(7)
    DO_STEP(8)  DO_STEP(9)  DO_STEP(10) DO_STEP(11)
    DO_STEP(12) DO_STEP(13) DO_STEP(14) DO_STEP(15)
#undef DO_STEP
#undef PHASE
#undef MFMA1

    // ---- epilogue: D col = o (l16), reg axis = contiguous n -> float4 ----
    float* ob = out + (size_t)b * CDIM * SDIM + n0;
    #pragma unroll
    for (int oi = 0; oi < 2; oi++) {
        const int o = wave * 32 + oi * 16 + l16;
        #pragma unroll
        for (int mi = 0; mi < 8; mi++)
            *(f32x4*)(ob + (size_t)o * SDIM + mi * 16 + quad * 4) = acc[mi][oi];
    }
}

// ---------------------------------------------------------------------------
extern "C" void kernel_launch(void* const* d_in, const int* in_sizes, int n_in,
                              void* d_out, int out_size, void* d_ws, size_t ws_size,
                              hipStream_t stream) {
    const float* x = (const float*)d_in[0];   // [16, 512, 64, 64]
    const float* V = (const float*)d_in[1];   // [32, 512]
    float* out = (float*)d_out;               // [16, 512, 64, 64] fp32

    __hip_bfloat16* Wt = (__hip_bfloat16*)d_ws;   // 512 KB frag-tiled W

    compute_w<<<64, 256, 0, stream>>>(V, Wt);
    hh_gemm<<<512, 1024, 0, stream>>>(x, Wt, out);
}